// Round 9
// baseline (9538.458 us; speedup 1.0000x reference)
//
#include <hip/hip_runtime.h>
#include <hip/hip_bf16.h>

typedef __attribute__((ext_vector_type(8))) short bf16x8;
typedef __attribute__((ext_vector_type(4))) float f32x4;

#define C2LE 2.8853900817779268f   // 2*log2(e)
#define LOG2E 1.4426950408889634f
#define AGENT __HIP_MEMORY_SCOPE_AGENT
#define RLX __ATOMIC_RELAXED

static __device__ __forceinline__ float blo(unsigned q) { return __uint_as_float(q << 16); }
static __device__ __forceinline__ float bhi(unsigned q) { return __uint_as_float(q & 0xFFFF0000u); }
static __device__ __forceinline__ float rterm(float arg) {
  return __builtin_amdgcn_rcpf(1.0f + __builtin_amdgcn_exp2f(arg));
}
static __device__ __forceinline__ float sigm(float x) {
  return __builtin_amdgcn_rcpf(1.0f + __builtin_amdgcn_exp2f(-x * LOG2E));
}
static __device__ __forceinline__ float tanhe(float x) {
  return fmaf(-2.0f, __builtin_amdgcn_rcpf(1.0f + __builtin_amdgcn_exp2f(x * C2LE)), 1.0f);
}
static __device__ __forceinline__ unsigned packhilo(float x) {
  __hip_bfloat16 h = __float2bfloat16(x);
  float r = x - __bfloat162float(h);
  __hip_bfloat16 l = __float2bfloat16(r);
  return (unsigned)__bfloat16_as_ushort(h) | ((unsigned)__bfloat16_as_ushort(l) << 16);
}
// paired uints (hi|lo<<16 per dim) -> hi/lo bf16x8 frags
static __device__ __forceinline__ void mkfrags(uint4 q0, uint4 q1, bf16x8& hi, bf16x8& lo) {
  uint4 h, l;
  h.x = __builtin_amdgcn_perm(q0.y, q0.x, 0x05040100u);
  h.y = __builtin_amdgcn_perm(q0.w, q0.z, 0x05040100u);
  h.z = __builtin_amdgcn_perm(q1.y, q1.x, 0x05040100u);
  h.w = __builtin_amdgcn_perm(q1.w, q1.z, 0x05040100u);
  l.x = __builtin_amdgcn_perm(q0.y, q0.x, 0x07060302u);
  l.y = __builtin_amdgcn_perm(q0.w, q0.z, 0x07060302u);
  l.z = __builtin_amdgcn_perm(q1.y, q1.x, 0x07060302u);
  l.w = __builtin_amdgcn_perm(q1.w, q1.z, 0x07060302u);
  hi = *(bf16x8*)&h;
  lo = *(bf16x8*)&l;
}
static __device__ __forceinline__ int swz(int e) { return e ^ ((e >> 4) & 7); }

// ---------------- pack kernels (R8-validated layouts) ----------------
// whB[sl16][nb2][kap16][l64][j8]: o = sl*32+nb*16+(l&15); dim = kap*32+(l>>4)*8+j
__global__ void k_pack_whB(const float* __restrict__ wue, __hip_bfloat16* __restrict__ wp) {
  for (int idx = blockIdx.x * blockDim.x + threadIdx.x; idx < 262144;
       idx += gridDim.x * blockDim.x) {
    int j = idx & 7, l = (idx >> 3) & 63, kap = (idx >> 9) & 15, nb = (idx >> 13) & 1,
        sl = idx >> 14;
    int o = sl * 32 + nb * 16 + (l & 15);
    int dim = kap * 32 + (l >> 4) * 8 + j;
    wp[idx] = __float2bfloat16(wue[o * 1024 + dim]);
  }
}
// w3B[sl16][ty4][ks12][l64][j8]: g = ty*256+sl*16+(l&15); k = ks*32+(l>>4)*8+j
__global__ void k_pack_w3B(const float* __restrict__ wih, const float* __restrict__ whh,
                           __hip_bfloat16* __restrict__ wp) {
  for (int idx = blockIdx.x * blockDim.x + threadIdx.x; idx < 393216;
       idx += gridDim.x * blockDim.x) {
    int j = idx & 7, l = (idx >> 3) & 63;
    int rest = idx >> 9;
    int ks = rest % 12, r = rest / 12;
    int ty = r & 3, sl = r >> 2;
    int g = ty * 256 + sl * 16 + (l & 15);
    int k = ks * 32 + (l >> 4) * 8 + j;
    float v = (k < 128) ? wih[g * 128 + k] : whh[g * 256 + (k - 128)];
    wp[idx] = __float2bfloat16(v);
  }
}
__global__ void k_bsum(const float* __restrict__ bih, const float* __restrict__ bhh,
                       float* __restrict__ bs) {
  int idx = blockIdx.x * blockDim.x + threadIdx.x;
  if (idx < 1024) bs[idx] = bih[idx] + bhh[idx];
}
__global__ void k_wxt(const float* __restrict__ wue, float* __restrict__ wxt) {
  for (int idx = blockIdx.x * blockDim.x + threadIdx.x; idx < 512 * 512;
       idx += gridDim.x * blockDim.x) {
    int o = idx & 511, s = idx >> 9;
    wxt[idx] = wue[o * 1024 + 512 + s];
  }
}

// proj_x: px2[b][d][s] = bf16(C2LE * proj_x[b,d,s])
__global__ __launch_bounds__(512) void k_projx(const float* __restrict__ x,
                                               const float* __restrict__ wxt,
                                               __hip_bfloat16* __restrict__ px2) {
  __shared__ alignas(16) float xsT[32][512];
  const int b = blockIdx.x;
  const int tid = threadIdx.x;
  for (int dt = 0; dt < 4; ++dt) {
    __syncthreads();
    const float4* xr = (const float4*)(x + ((size_t)b << 16) + (size_t)tid * 128 + dt * 32);
#pragma unroll
    for (int q = 0; q < 8; ++q) {
      float4 vx = xr[q];
      xsT[q * 4 + 0][tid] = vx.x;
      xsT[q * 4 + 1][tid] = vx.y;
      xsT[q * 4 + 2][tid] = vx.z;
      xsT[q * 4 + 3][tid] = vx.w;
    }
    __syncthreads();
    const int o = tid;
    float acc[32];
#pragma unroll
    for (int dd = 0; dd < 32; ++dd) acc[dd] = 0.f;
    for (int s4 = 0; s4 < 128; ++s4) {
      float w0 = wxt[(s4 * 4 + 0) * 512 + o];
      float w1 = wxt[(s4 * 4 + 1) * 512 + o];
      float w2 = wxt[(s4 * 4 + 2) * 512 + o];
      float w3 = wxt[(s4 * 4 + 3) * 512 + o];
#pragma unroll
      for (int dd = 0; dd < 32; ++dd) {
        float4 xv = *(const float4*)&xsT[dd][s4 * 4];
        acc[dd] = fmaf(w0, xv.x, fmaf(w1, xv.y, fmaf(w2, xv.z, fmaf(w3, xv.w, acc[dd]))));
      }
    }
    for (int dd = 0; dd < 32; ++dd) {
      px2[((size_t)b * 128 + dt * 32 + dd) * 512 + o] = __float2bfloat16(acc[dd] * C2LE);
    }
  }
}

// ---------------- main: 256 blocks = 16 slices x 16 group-pairs; 2 chains/block ----
__global__ __launch_bounds__(1024, 4) void k_main(
    const __hip_bfloat16* __restrict__ px2, const __hip_bfloat16* __restrict__ whB,
    const __hip_bfloat16* __restrict__ w3B, const float* __restrict__ bsum,
    const float* __restrict__ x, const float* __restrict__ ve,
    unsigned* __restrict__ hG, float* __restrict__ Eg, unsigned* __restrict__ ctrs,
    float* __restrict__ out) {
  __shared__ alignas(16) __hip_bfloat16 w3_l[24576];                  // 48 KB (shared by chains)
  __shared__ alignas(16) uint4 hA0A[1024], hA1A[1024];                // 32 KB chain A
  __shared__ alignas(16) uint4 hA0B[1024], hA1B[1024];                // 32 KB chain B
  __shared__ alignas(16) uint4 unA[512], unB[512];                    // 8 KB each: PHp | uA0+uA1
  __shared__ alignas(16) float PHA[256], PHB[256];
  __shared__ alignas(16) float gpA[4 * 64 * 9], gpB[4 * 64 * 9];      // 9 KB each
  __shared__ float c_lA[128], c_lB[128];
  __shared__ float v_l[32], bs_l[64], zpA[16], zpB[16];
  __shared__ float vss_sh;

  const int gpi = blockIdx.x & 15;  // group-pair; members of a group share blockIdx%16 -> same XCD
  const int sl = blockIdx.x >> 4;   // slice 0..15
  const int gA = gpi * 2, gB = gpi * 2 + 1;
  const int tid = threadIdx.x, lane = tid & 63, w = tid >> 6;
  const int b = tid >> 7, d = tid & 127;

  // ---- prologue
  for (int i = tid; i < 3072; i += 1024)
    ((uint4*)w3_l)[i] = ((const uint4*)(w3B + (size_t)sl * 24576))[i];
  bf16x8 whr[2];
  {
    const int nb = w & 1, kq = w >> 1;
    const bf16x8* src = (const bf16x8*)whB + ((size_t)(sl * 2 + nb) * 16 + kq * 2) * 64 + lane;
    whr[0] = src[0];
    whr[1] = src[64];
  }
  uint4 pxrA[4], pxrB[4];
  {
    const uint4* pA = (const uint4*)(px2 + ((size_t)(gA * 8 + b) * 128 + d) * 512 + sl * 32);
    const uint4* pB = (const uint4*)(px2 + ((size_t)(gB * 8 + b) * 128 + d) * 512 + sl * 32);
#pragma unroll
    for (int i = 0; i < 4; ++i) {
      pxrA[i] = pA[i];
      pxrB[i] = pB[i];
    }
  }
  if (tid < 32) v_l[tid] = ve[sl * 32 + tid];
  if (tid < 64) bs_l[tid] = bsum[(tid >> 4) * 256 + sl * 16 + (tid & 15)];
  if (tid < 128) {
    c_lA[tid] = 0.f;
    c_lB[tid] = 0.f;
  }
  if (tid == 0) {
    float s = 0.f;
    for (int i = 0; i < 32; ++i) s += ve[sl * 32 + i];
    vss_sh = s;
  }
  __syncthreads();
  const float vss = vss_sh;
  unsigned* ctrAA = ctrs + gA * 64;
  unsigned* ctrBA = ctrAA + 32;
  unsigned* ctrAB = ctrs + gB * 64;
  unsigned* ctrBB = ctrAB + 32;
  float xvA = x[((size_t)(gA * 8 + b) * 512) * 128 + d];
  float xvB = x[((size_t)(gB * 8 + b) * 512) * 128 + d];

  auto gwait = [&](unsigned* c, unsigned tgt) {
    if (tid == 0) {
      while (__hip_atomic_load(c, RLX, AGENT) < tgt) __builtin_amdgcn_s_sleep(1);
    }
    __syncthreads();
  };
  auto issue = [&](int g, int par, unsigned long long& a0, unsigned long long& a1) {
    const unsigned long long* hp =
        (const unsigned long long*)(hG + (size_t)(par * 32 + g) * 4096) + tid * 2;
    a0 = __hip_atomic_load(hp, RLX, AGENT);
    a1 = __hip_atomic_load(hp + 1, RLX, AGENT);
  };
  auto front = [&](int g, uint4* hA0, uint4* hA1, float* PHp, float* PH, const uint4* pxr,
                   unsigned* ctrA_, int par, unsigned long long a0, unsigned long long a1) {
    {
      int p = tid * 4;
      int ep = swz(((p >> 6) << 4) + ((p >> 3) & 7));
      uint4 q;
      q.x = (unsigned)a0;
      q.y = (unsigned)(a0 >> 32);
      q.z = (unsigned)a1;
      q.w = (unsigned)(a1 >> 32);
      if (p & 4) hA1[ep] = q;
      else hA0[ep] = q;
    }
    if (tid < 64)
      __hip_atomic_store(Eg + (size_t)((1 - par) * 32 + g) * 1024 + sl * 64 + tid, 0.f, RLX,
                         AGENT);
    __syncthreads();
    // P1: PH[8b,32o] = [h;c] x Wh (16 waves = 2nb x 8kq; hi+lo)
    {
      const int kq = w >> 1, nb = w & 1;
      f32x4 acc = {0.f, 0.f, 0.f, 0.f};
#pragma unroll
      for (int i = 0; i < 2; ++i) {
        int ep = swz((kq * 2 + i) * 64 + lane);
        uint4 q0 = hA0[ep], q1 = hA1[ep];
        bf16x8 ahi, alo;
        mkfrags(q0, q1, ahi, alo);
        acc = __builtin_amdgcn_mfma_f32_16x16x32_bf16(ahi, whr[i], acc, 0, 0, 0);
        acc = __builtin_amdgcn_mfma_f32_16x16x32_bf16(alo, whr[i], acc, 0, 0, 0);
      }
      if (lane < 32) {
        int r16 = lane >> 4, c16 = lane & 15;
#pragma unroll
        for (int rr = 0; rr < 4; ++rr)
          PHp[(kq * 8 + r16 * 4 + rr) * 32 + nb * 16 + c16] = acc[rr];
      }
    }
    __syncthreads();
    if (tid < 256) {
      int bb = tid >> 5, o = tid & 31;
      float s = ((PHp[(0 * 8 + bb) * 32 + o] + PHp[(1 * 8 + bb) * 32 + o]) +
                 (PHp[(2 * 8 + bb) * 32 + o] + PHp[(3 * 8 + bb) * 32 + o])) +
                ((PHp[(4 * 8 + bb) * 32 + o] + PHp[(5 * 8 + bb) * 32 + o]) +
                 (PHp[(6 * 8 + bb) * 32 + o] + PHp[(7 * 8 + bb) * 32 + o]));
      PH[tid] = s * C2LE;
    }
    __syncthreads();
    // P2: E partial over 32 s; one atomicAdd
    {
      float R = 0.f;
      const float* PHb = &PH[b * 32];
#pragma unroll
      for (int s8 = 0; s8 < 4; ++s8) {
        uint4 q = pxr[s8];
        float4 pa = *(const float4*)&PHb[s8 * 8];
        float4 pb = *(const float4*)&PHb[s8 * 8 + 4];
        float4 va = *(const float4*)&v_l[s8 * 8];
        float4 vb = *(const float4*)&v_l[s8 * 8 + 4];
        R = fmaf(va.x, rterm(pa.x + blo(q.x)), R);
        R = fmaf(va.y, rterm(pa.y + bhi(q.x)), R);
        R = fmaf(va.z, rterm(pa.z + blo(q.y)), R);
        R = fmaf(va.w, rterm(pa.w + bhi(q.y)), R);
        R = fmaf(vb.x, rterm(pb.x + blo(q.z)), R);
        R = fmaf(vb.y, rterm(pb.y + bhi(q.z)), R);
        R = fmaf(vb.z, rterm(pb.z + blo(q.w)), R);
        R = fmaf(vb.w, rterm(pb.w + bhi(q.w)), R);
      }
      __hip_atomic_fetch_add(Eg + (size_t)(par * 32 + g) * 1024 + b * 128 + d,
                             fmaf(-2.f, R, vss), RLX, AGENT);
    }
    __syncthreads();
    if (tid == 0) __hip_atomic_fetch_add(ctrA_, 1u, RLX, AGENT);
  };
  auto back = [&](int g, uint4* hA0, uint4* hA1, uint4* un, float* gpp, float* c_l, float* zp,
                  float& xv, unsigned* ctrB_, int par, int t) {
    uint4* uA0 = un;
    uint4* uA1 = un + 256;
    float Ev = __hip_atomic_load(Eg + (size_t)(par * 32 + g) * 1024 + b * 128 + d, RLX, AGENT);
    float e = __builtin_amdgcn_exp2f(Ev * LOG2E);
    {
      float z = e;
#pragma unroll
      for (int m = 1; m < 64; m <<= 1) z += __shfl_xor(z, m);
      if (lane == 0) zp[w] = z;
    }
    __syncthreads();
    {
      float zf = zp[2 * b] + zp[2 * b + 1];
      float u = xv * e * __builtin_amdgcn_rcpf(zf);
      int ep = swz((d >> 5) * 64 + ((d >> 3) & 3) * 16 + b);
      unsigned* dst = (d & 4) ? (unsigned*)&uA1[ep] : (unsigned*)&uA0[ep];
      dst[d & 3] = packhilo(u);
    }
    __syncthreads();
    // P3: gates (16 waves = 4 ty x 4 kh; 3 ks each; W3 from LDS)
    {
      const int ty3 = w & 3, kh3 = w >> 2;
      f32x4 acc = {0.f, 0.f, 0.f, 0.f};
#pragma unroll
      for (int i = 0; i < 3; ++i) {
        int ks = kh3 * 3 + i;
        uint4 q0, q1;
        if (ks < 4) {
          int ep = swz(ks * 64 + lane);
          q0 = uA0[ep];
          q1 = uA1[ep];
        } else {
          int ep = swz((ks - 4) * 64 + lane);
          q0 = hA0[ep];
          q1 = hA1[ep];
        }
        bf16x8 ahi, alo;
        mkfrags(q0, q1, ahi, alo);
        bf16x8 bf = ((const bf16x8*)w3_l)[((size_t)ty3 * 12 + ks) * 64 + lane];
        acc = __builtin_amdgcn_mfma_f32_16x16x32_bf16(ahi, bf, acc, 0, 0, 0);
        acc = __builtin_amdgcn_mfma_f32_16x16x32_bf16(alo, bf, acc, 0, 0, 0);
      }
      if (lane < 32) {
        int r16 = lane >> 4, c16 = lane & 15;
#pragma unroll
        for (int rr = 0; rr < 4; ++rr)
          gpp[(kh3 * 64 + ty3 * 16 + c16) * 9 + r16 * 4 + rr] = acc[rr];
      }
    }
    __syncthreads();
    // P4: LSTM pointwise + publish
    float h_new = 0.f;
    int bb = tid & 7, jj = tid >> 3;
    if (tid < 128) {
      float gi = gpp[(0 * 64 + jj) * 9 + bb] + gpp[(1 * 64 + jj) * 9 + bb] +
                 gpp[(2 * 64 + jj) * 9 + bb] + gpp[(3 * 64 + jj) * 9 + bb] + bs_l[jj];
      float gf = gpp[(0 * 64 + 16 + jj) * 9 + bb] + gpp[(1 * 64 + 16 + jj) * 9 + bb] +
                 gpp[(2 * 64 + 16 + jj) * 9 + bb] + gpp[(3 * 64 + 16 + jj) * 9 + bb] +
                 bs_l[16 + jj];
      float gg = gpp[(0 * 64 + 32 + jj) * 9 + bb] + gpp[(1 * 64 + 32 + jj) * 9 + bb] +
                 gpp[(2 * 64 + 32 + jj) * 9 + bb] + gpp[(3 * 64 + 32 + jj) * 9 + bb] +
                 bs_l[32 + jj];
      float go = gpp[(0 * 64 + 48 + jj) * 9 + bb] + gpp[(1 * 64 + 48 + jj) * 9 + bb] +
                 gpp[(2 * 64 + 48 + jj) * 9 + bb] + gpp[(3 * 64 + 48 + jj) * 9 + bb] +
                 bs_l[48 + jj];
      float i_ = sigm(gi), f_ = sigm(gf), g_ = tanhe(gg), o_ = sigm(go);
      float c_new = fmaf(f_, c_l[jj * 8 + bb], i_ * g_);
      h_new = o_ * tanhe(c_new);
      c_l[jj * 8 + bb] = c_new;
      int dd = sl * 16 + jj;
      int p = (((dd >> 5) * 4 + ((dd >> 3) & 3)) * 8 + bb) * 8 + (dd & 7);
      unsigned* hw = hG + (size_t)((1 - par) * 32 + g) * 4096;
      __hip_atomic_store(hw + p, packhilo(h_new), RLX, AGENT);
      __hip_atomic_store(hw + p + 2048, packhilo(c_new), RLX, AGENT);
    }
    __syncthreads();
    if (tid == 0) __hip_atomic_fetch_add(ctrB_, 1u, RLX, AGENT);
    if (tid < 128)
      __builtin_nontemporal_store(h_new,
                                  out + ((size_t)t * 256 + g * 8 + bb) * 256 + sl * 16 + jj);
    int tn = (t < 511) ? t + 1 : 511;
    xv = x[((size_t)(g * 8 + b) * 512 + tn) * 128 + d];
  };

  for (int t = 0; t < 512; ++t) {
    const int par = t & 1;
    gwait(ctrBA, 16u * t);
    unsigned long long aA0, aA1;
    issue(gA, par, aA0, aA1);
    gwait(ctrBB, 16u * t);
    unsigned long long aB0, aB1;
    issue(gB, par, aB0, aB1);
    front(gA, hA0A, hA1A, (float*)unA, PHA, pxrA, ctrAA, par, aA0, aA1);
    front(gB, hA0B, hA1B, (float*)unB, PHB, pxrB, ctrAB, par, aB0, aB1);
    gwait(ctrAA, 16u * (t + 1));
    back(gA, hA0A, hA1A, unA, gpA, c_lA, zpA, xvA, ctrBA, par, t);
    gwait(ctrAB, 16u * (t + 1));
    back(gB, hA0B, hA1B, unB, gpB, c_lB, zpB, xvB, ctrBB, par, t);
  }
}

// ---------------- host ----------------
extern "C" void kernel_launch(void* const* d_in, const int* in_sizes, int n_in,
                              void* d_out, int out_size, void* d_ws, size_t ws_size,
                              hipStream_t stream) {
  const float* x = (const float*)d_in[0];
  const float* wue = (const float*)d_in[1];
  const float* ve = (const float*)d_in[2];
  const float* wih = (const float*)d_in[3];
  const float* whh = (const float*)d_in[4];
  const float* bih = (const float*)d_in[5];
  const float* bhh = (const float*)d_in[6];
  float* out = (float*)d_out;

  char* ws = (char*)d_ws;
  __hip_bfloat16* px2 = (__hip_bfloat16*)(ws);             // 33,554,432 B
  __hip_bfloat16* whB = (__hip_bfloat16*)(ws + 33554432);  //    524,288 B
  __hip_bfloat16* w3B = (__hip_bfloat16*)(ws + 34078720);  //    786,432 B
  float* bsum = (float*)(ws + 34865152);                   //      4,096 B
  float* Eg = (float*)(ws + 34869248);                     //    262,144 B
  unsigned* ctrs = (unsigned*)(ws + 35131392);             //      8,192 B
  unsigned* hG = (unsigned*)(ws + 35139584);               //  1,048,576 B
  float* wxt = (float*)(ws + 36188160);                    //  1,048,576 B
  // total: 37,236,736 B

  k_pack_whB<<<1024, 256, 0, stream>>>(wue, whB);
  k_pack_w3B<<<1024, 256, 0, stream>>>(wih, whh, w3B);
  k_bsum<<<4, 256, 0, stream>>>(bih, bhh, bsum);
  k_wxt<<<256, 256, 0, stream>>>(wue, wxt);
  k_projx<<<256, 512, 0, stream>>>(x, wxt, px2);
  hipMemsetAsync(hG, 0, 1048576, stream);
  hipMemsetAsync(Eg, 0, 262144, stream);
  hipMemsetAsync(ctrs, 0, 8192, stream);
  k_main<<<256, 1024, 0, stream>>>(px2, whB, w3B, bsum, x, ve, hG, Eg, ctrs, out);
}

// Round 10
// 4630.581 us; speedup vs baseline: 2.0599x; 2.0599x over previous
//
#include <hip/hip_runtime.h>
#include <hip/hip_bf16.h>

typedef __attribute__((ext_vector_type(8))) short bf16x8;
typedef __attribute__((ext_vector_type(4))) float f32x4;

#define C2LE 2.8853900817779268f   // 2*log2(e)
#define LOG2E 1.4426950408889634f
#define AGENT __HIP_MEMORY_SCOPE_AGENT
#define RLX __ATOMIC_RELAXED

static __device__ __forceinline__ float blo(unsigned q) { return __uint_as_float(q << 16); }
static __device__ __forceinline__ float bhi(unsigned q) { return __uint_as_float(q & 0xFFFF0000u); }
static __device__ __forceinline__ float sigm(float x) {
  return __builtin_amdgcn_rcpf(1.0f + __builtin_amdgcn_exp2f(-x * LOG2E));
}
static __device__ __forceinline__ float tanhe(float x) {
  return fmaf(-2.0f, __builtin_amdgcn_rcpf(1.0f + __builtin_amdgcn_exp2f(x * C2LE)), 1.0f);
}
static __device__ __forceinline__ unsigned packhilo(float x) {
  __hip_bfloat16 h = __float2bfloat16(x);
  float r = x - __bfloat162float(h);
  __hip_bfloat16 l = __float2bfloat16(r);
  return (unsigned)__bfloat16_as_ushort(h) | ((unsigned)__bfloat16_as_ushort(l) << 16);
}
// paired uints (hi|lo<<16 per dim) -> hi/lo bf16x8 frags
static __device__ __forceinline__ void mkfrags(uint4 q0, uint4 q1, bf16x8& hi, bf16x8& lo) {
  uint4 h, l;
  h.x = __builtin_amdgcn_perm(q0.y, q0.x, 0x05040100u);
  h.y = __builtin_amdgcn_perm(q0.w, q0.z, 0x05040100u);
  h.z = __builtin_amdgcn_perm(q1.y, q1.x, 0x05040100u);
  h.w = __builtin_amdgcn_perm(q1.w, q1.z, 0x05040100u);
  l.x = __builtin_amdgcn_perm(q0.y, q0.x, 0x07060302u);
  l.y = __builtin_amdgcn_perm(q0.w, q0.z, 0x07060302u);
  l.z = __builtin_amdgcn_perm(q1.y, q1.x, 0x07060302u);
  l.w = __builtin_amdgcn_perm(q1.w, q1.z, 0x07060302u);
  hi = *(bf16x8*)&h;
  lo = *(bf16x8*)&l;
}
static __device__ __forceinline__ int swz(int e) { return e ^ ((e >> 4) & 7); }

// ---------------- pack kernels (R6/R7-validated layouts) ----------------
__global__ void k_pack_whB(const float* __restrict__ wue, __hip_bfloat16* __restrict__ wp) {
  for (int idx = blockIdx.x * blockDim.x + threadIdx.x; idx < 262144;
       idx += gridDim.x * blockDim.x) {
    int j = idx & 7, l = (idx >> 3) & 63, kap = (idx >> 9) & 15, nb = (idx >> 13) & 3,
        sl = idx >> 15;
    int o = sl * 64 + nb * 16 + (l & 15);
    int dim = kap * 32 + (l >> 4) * 8 + j;
    wp[idx] = __float2bfloat16(wue[o * 1024 + dim]);
  }
}
__global__ void k_pack_w3B(const float* __restrict__ wih, const float* __restrict__ whh,
                           __hip_bfloat16* __restrict__ wp) {
  for (int idx = blockIdx.x * blockDim.x + threadIdx.x; idx < 393216;
       idx += gridDim.x * blockDim.x) {
    int j = idx & 7, l = (idx >> 3) & 63;
    int ks = (idx >> 9) % 12, r = (idx >> 9) / 12;
    int nb = r & 7, sl = r >> 3;
    int n = nb * 16 + (l & 15);
    int g = (n >> 5) * 256 + sl * 32 + (n & 31);
    int k = ks * 32 + (l >> 4) * 8 + j;
    float v = (k < 128) ? wih[g * 128 + k] : whh[g * 256 + (k - 128)];
    wp[idx] = __float2bfloat16(v);
  }
}
__global__ void k_bsum(const float* __restrict__ bih, const float* __restrict__ bhh,
                       float* __restrict__ bs) {
  int idx = blockIdx.x * blockDim.x + threadIdx.x;
  if (idx < 1024) bs[idx] = bih[idx] + bhh[idx];
}
__global__ void k_wxt(const float* __restrict__ wue, float* __restrict__ wxt) {
  for (int idx = blockIdx.x * blockDim.x + threadIdx.x; idx < 512 * 512;
       idx += gridDim.x * blockDim.x) {
    int o = idx & 511, s = idx >> 9;
    wxt[idx] = wue[o * 1024 + 512 + s];
  }
}

// proj_x: px2[b][d][s] = bf16( exp2(C2LE * proj_x[b,d,s]) )   [Epx]
__global__ __launch_bounds__(512) void k_projx(const float* __restrict__ x,
                                               const float* __restrict__ wxt,
                                               __hip_bfloat16* __restrict__ px2) {
  __shared__ alignas(16) float xsT[32][512];
  const int b = blockIdx.x;
  const int tid = threadIdx.x;
  for (int dt = 0; dt < 4; ++dt) {
    __syncthreads();
    const float4* xr = (const float4*)(x + ((size_t)b << 16) + (size_t)tid * 128 + dt * 32);
#pragma unroll
    for (int q = 0; q < 8; ++q) {
      float4 vx = xr[q];
      xsT[q * 4 + 0][tid] = vx.x;
      xsT[q * 4 + 1][tid] = vx.y;
      xsT[q * 4 + 2][tid] = vx.z;
      xsT[q * 4 + 3][tid] = vx.w;
    }
    __syncthreads();
    const int o = tid;
    float acc[32];
#pragma unroll
    for (int dd = 0; dd < 32; ++dd) acc[dd] = 0.f;
    for (int s4 = 0; s4 < 128; ++s4) {
      float w0 = wxt[(s4 * 4 + 0) * 512 + o];
      float w1 = wxt[(s4 * 4 + 1) * 512 + o];
      float w2 = wxt[(s4 * 4 + 2) * 512 + o];
      float w3 = wxt[(s4 * 4 + 3) * 512 + o];
#pragma unroll
      for (int dd = 0; dd < 32; ++dd) {
        float4 xv = *(const float4*)&xsT[dd][s4 * 4];
        acc[dd] = fmaf(w0, xv.x, fmaf(w1, xv.y, fmaf(w2, xv.z, fmaf(w3, xv.w, acc[dd]))));
      }
    }
    for (int dd = 0; dd < 32; ++dd) {
      px2[((size_t)b * 128 + dt * 32 + dd) * 512 + o] =
          __float2bfloat16(__builtin_amdgcn_exp2f(acc[dd] * C2LE));
    }
  }
}

// ---------------- main persistent kernel: 32 groups x 8 blocks ----------------
__global__ __launch_bounds__(1024) void k_main(
    const __hip_bfloat16* __restrict__ px2, const __hip_bfloat16* __restrict__ whB,
    const __hip_bfloat16* __restrict__ w3B, const float* __restrict__ bsum,
    const float* __restrict__ x, const float* __restrict__ ve,
    unsigned* __restrict__ hG, float* __restrict__ Eg, unsigned* __restrict__ ctrs,
    float* __restrict__ out) {
  __shared__ alignas(16) __hip_bfloat16 w3_l[49152];  // 96 KB W3 B-frags
  __shared__ alignas(16) uint4 hA0[1024];             // 16 KB (q0 halves, swizzled)
  __shared__ alignas(16) uint4 hA1[1024];             // 16 KB (q1 halves)
  __shared__ alignas(16) uint4 uA0[256];              // 4 KB
  __shared__ alignas(16) uint4 uA1[256];              // 4 KB
  __shared__ float PHp[4][8][64];                     // 8 KB
  __shared__ float PH[512];                           // 2 KB   ePH = exp2(C2LE*ph)
  __shared__ float gp[2][128][9];                     // 9 KB (padded stride)
  __shared__ float c_l[32][8];                        // 1 KB
  __shared__ float v_l[64];
  __shared__ float bs_l[128];
  __shared__ float zpart[16];
  __shared__ float vss_sh;

  const int grp = blockIdx.x & 31;  // 8 member blocks share blockIdx%32 -> same XCD
  const int sl = blockIdx.x >> 5;   // slice 0..7
  const int tid = threadIdx.x;
  const int lane = tid & 63;
  const int w = tid >> 6;
  const int b = tid >> 7;  // phase2/softmax mapping
  const int d = tid & 127;
  const int bG = grp * 8 + b;

  // ---- prologue
  {
    const uint4* src = (const uint4*)(w3B + (size_t)sl * 49152);
    uint4* dst = (uint4*)w3_l;
    for (int i = tid; i < 6144; i += 1024) dst[i] = src[i];
  }
  bf16x8 whr[4];
  {
    const bf16x8* src =
        (const bf16x8*)whB + ((size_t)(sl * 4 + (w & 3)) * 16 + (w >> 2) * 4) * 64 + lane;
#pragma unroll
    for (int i = 0; i < 4; ++i) whr[i] = src[i * 64];
  }
  uint4 pxr[8];  // bf16 Epx pairs for our (b,d), 64 s
  {
    const uint4* p4 = (const uint4*)(px2 + ((size_t)bG * 128 + d) * 512 + sl * 64);
#pragma unroll
    for (int i = 0; i < 8; ++i) pxr[i] = p4[i];
  }
  if (tid < 64) v_l[tid] = ve[sl * 64 + tid];
  if (tid < 128) bs_l[tid] = bsum[(tid >> 5) * 256 + sl * 32 + (tid & 31)];
  if (tid < 256) c_l[tid >> 3][tid & 7] = 0.f;
  {
    uint4 z = {0, 0, 0, 0};
    hA0[tid] = z;
    hA1[tid] = z;
    if (tid < 256) {
      uA0[tid] = z;
      uA1[tid] = z;
    }
  }
  if (tid == 0) {
    float s = 0.f;
    for (int i = 0; i < 64; ++i) s += ve[sl * 64 + i];
    vss_sh = s;
  }
  __syncthreads();
  const float vss = vss_sh;
  unsigned* ctrA = ctrs + grp * 64;
  unsigned* ctrB = ctrA + 32;
  float xv = x[((size_t)bG * 512) * 128 + d];  // x for t=0

  for (int t = 0; t < 512; ++t) {
    const int par = t & 1;

    // ---- stage h/c (compact) from coherence point into swizzled split LDS arrays
    {
      const unsigned long long* hp =
          (const unsigned long long*)(hG + (size_t)(par * 32 + grp) * 4096) + tid * 2;
      unsigned long long a0 = __hip_atomic_load(hp, RLX, AGENT);
      unsigned long long a1 = __hip_atomic_load(hp + 1, RLX, AGENT);
      int p = tid * 4;
      int e = ((p >> 6) << 4) + ((p >> 3) & 7);
      int ep = swz(e);
      uint4 q;
      q.x = (unsigned)a0;
      q.y = (unsigned)(a0 >> 32);
      q.z = (unsigned)a1;
      q.w = (unsigned)(a1 >> 32);
      if (p & 4) hA1[ep] = q;
      else hA0[ep] = q;
    }
    // zero next-par E slice (ours: 128 dwords)
    if (tid < 128)
      __hip_atomic_store(Eg + (size_t)((1 - par) * 32 + grp) * 1024 + sl * 128 + tid, 0.f, RLX,
                         AGENT);
    __syncthreads();

    // ---- Phase 1: PH[8b, 64o] = hs x Wh (16 waves = 4nb x 4kq; hi+lo passes)
    {
      const int kq = w >> 2, nb = w & 3;
      f32x4 acc = {0.f, 0.f, 0.f, 0.f};
#pragma unroll
      for (int i = 0; i < 4; ++i) {
        int ep = swz((kq * 4 + i) * 64 + lane);
        uint4 q0 = hA0[ep], q1 = hA1[ep];
        bf16x8 ahi, alo;
        mkfrags(q0, q1, ahi, alo);
        acc = __builtin_amdgcn_mfma_f32_16x16x32_bf16(ahi, whr[i], acc, 0, 0, 0);
        acc = __builtin_amdgcn_mfma_f32_16x16x32_bf16(alo, whr[i], acc, 0, 0, 0);
      }
      if (lane < 32) {
        int r16 = lane >> 4, c16 = lane & 15;
#pragma unroll
        for (int rr = 0; rr < 4; ++rr) PHp[kq][r16 * 4 + rr][nb * 16 + c16] = acc[rr];
      }
    }
    __syncthreads();
    if (tid < 512) {
      float s = (PHp[0][tid >> 6][tid & 63] + PHp[1][tid >> 6][tid & 63] +
                 PHp[2][tid >> 6][tid & 63] + PHp[3][tid >> 6][tid & 63]);
      PH[tid] = __builtin_amdgcn_exp2f(s * C2LE);  // ePH
    }
    __syncthreads();

    // ---- Phase 2: E partial over our 64 s for (b,d): r = 1/(1 + Epx*ePH)
    {
      float R = 0.f;
      const float* PHb = &PH[b * 64];
#pragma unroll 2
      for (int s8 = 0; s8 < 8; ++s8) {
        uint4 q = pxr[s8];
        float4 pa = *(const float4*)&PHb[s8 * 8];
        float4 pb = *(const float4*)&PHb[s8 * 8 + 4];
        float4 va = *(const float4*)&v_l[s8 * 8];
        float4 vb = *(const float4*)&v_l[s8 * 8 + 4];
        R = fmaf(va.x, __builtin_amdgcn_rcpf(fmaf(blo(q.x), pa.x, 1.0f)), R);
        R = fmaf(va.y, __builtin_amdgcn_rcpf(fmaf(bhi(q.x), pa.y, 1.0f)), R);
        R = fmaf(va.z, __builtin_amdgcn_rcpf(fmaf(blo(q.y), pa.z, 1.0f)), R);
        R = fmaf(va.w, __builtin_amdgcn_rcpf(fmaf(bhi(q.y), pa.w, 1.0f)), R);
        R = fmaf(vb.x, __builtin_amdgcn_rcpf(fmaf(blo(q.z), pb.x, 1.0f)), R);
        R = fmaf(vb.y, __builtin_amdgcn_rcpf(fmaf(bhi(q.z), pb.y, 1.0f)), R);
        R = fmaf(vb.z, __builtin_amdgcn_rcpf(fmaf(blo(q.w), pb.z, 1.0f)), R);
        R = fmaf(vb.w, __builtin_amdgcn_rcpf(fmaf(bhi(q.w), pb.w, 1.0f)), R);
      }
      __hip_atomic_fetch_add(Eg + (size_t)(par * 32 + grp) * 1024 + b * 128 + d,
                             fmaf(-2.f, R, vss), RLX, AGENT);
    }

    // ---- Phase 3h (h-part of gates; independent of softmax) hides barrier A
    const int nb3 = w & 7, kh3 = w >> 3;
    f32x4 acc3 = {0.f, 0.f, 0.f, 0.f};
#pragma unroll
    for (int i = 0; i < 4; ++i) {
      int ks = 4 + kh3 * 4 + i;  // h ksteps 4..11 -> hA entries 0..7
      int ep = swz((ks - 4) * 64 + lane);
      uint4 q0 = hA0[ep], q1 = hA1[ep];
      bf16x8 ahi, alo;
      mkfrags(q0, q1, ahi, alo);
      bf16x8 bf = ((const bf16x8*)w3_l)[((size_t)nb3 * 12 + ks) * 64 + lane];
      acc3 = __builtin_amdgcn_mfma_f32_16x16x32_bf16(ahi, bf, acc3, 0, 0, 0);
      acc3 = __builtin_amdgcn_mfma_f32_16x16x32_bf16(alo, bf, acc3, 0, 0, 0);
    }
    // ---- barrier A (arrive after syncthreads drains E-adds; poll exposed only past 3h)
    __syncthreads();
    if (tid == 0) {
      __hip_atomic_fetch_add(ctrA, 1u, RLX, AGENT);
      while (__hip_atomic_load(ctrA, RLX, AGENT) < 8u * (t + 1)) __builtin_amdgcn_s_sleep(1);
    }
    __syncthreads();

    // ---- softmax + u A-frag build
    float Ev = __hip_atomic_load(Eg + (size_t)(par * 32 + grp) * 1024 + b * 128 + d, RLX, AGENT);
    float e = __builtin_amdgcn_exp2f(Ev * LOG2E);
    {
      float z = e;
#pragma unroll
      for (int m = 1; m < 64; m <<= 1) z += __shfl_xor(z, m);
      if (lane == 0) zpart[w] = z;
    }
    __syncthreads();
    {
      float zf = zpart[2 * b] + zpart[2 * b + 1];
      float u = xv * e * __builtin_amdgcn_rcpf(zf);
      int ep = swz((d >> 5) * 64 + ((d >> 3) & 3) * 16 + b);
      unsigned* dst = (d & 4) ? (unsigned*)&uA1[ep] : (unsigned*)&uA0[ep];
      dst[d & 3] = packhilo(u);
    }
    __syncthreads();

    // ---- Phase 3u: u-part of gates (ks 0..3)
#pragma unroll
    for (int i = 0; i < 2; ++i) {
      int ks = kh3 * 2 + i;
      int ep = swz(ks * 64 + lane);
      uint4 q0 = uA0[ep], q1 = uA1[ep];
      bf16x8 ahi, alo;
      mkfrags(q0, q1, ahi, alo);
      bf16x8 bf = ((const bf16x8*)w3_l)[((size_t)nb3 * 12 + ks) * 64 + lane];
      acc3 = __builtin_amdgcn_mfma_f32_16x16x32_bf16(ahi, bf, acc3, 0, 0, 0);
      acc3 = __builtin_amdgcn_mfma_f32_16x16x32_bf16(alo, bf, acc3, 0, 0, 0);
    }
    if (lane < 32) {
      int r16 = lane >> 4, c16 = lane & 15;
#pragma unroll
      for (int rr = 0; rr < 4; ++rr) gp[kh3][nb3 * 16 + c16][r16 * 4 + rr] = acc3[rr];
    }
    __syncthreads();

    // ---- Phase 4: LSTM pointwise (8b x 32jj); publish h/c
    float h_new;
    if (tid < 256) {
      int bb = tid & 7, jj = tid >> 3;
      float gi = gp[0][jj][bb] + gp[1][jj][bb] + bs_l[jj];
      float gf = gp[0][32 + jj][bb] + gp[1][32 + jj][bb] + bs_l[32 + jj];
      float gg = gp[0][64 + jj][bb] + gp[1][64 + jj][bb] + bs_l[64 + jj];
      float go = gp[0][96 + jj][bb] + gp[1][96 + jj][bb] + bs_l[96 + jj];
      float i_ = sigm(gi), f_ = sigm(gf), g_ = tanhe(gg), o_ = sigm(go);
      float c_new = fmaf(f_, c_l[jj][bb], i_ * g_);
      h_new = o_ * tanhe(c_new);
      c_l[jj][bb] = c_new;
      int dd = sl * 32 + jj;
      int p = (((dd >> 5) * 4 + ((dd >> 3) & 3)) * 8 + bb) * 8 + (dd & 7);
      unsigned* hw = hG + (size_t)((1 - par) * 32 + grp) * 4096;
      __hip_atomic_store(hw + p, packhilo(h_new), RLX, AGENT);
      __hip_atomic_store(hw + p + 2048, packhilo(c_new), RLX, AGENT);
    }
    // ---- barrier B; fill the poll window with out-store + next-x prefetch
    __syncthreads();
    if (tid == 0) __hip_atomic_fetch_add(ctrB, 1u, RLX, AGENT);
    if (tid < 256) {
      int bb = tid & 7, jj = tid >> 3;
      __builtin_nontemporal_store(h_new,
                                  out + ((size_t)t * 256 + grp * 8 + bb) * 256 + sl * 32 + jj);
    }
    int tn = (t < 511) ? t + 1 : 511;
    float xv_n = x[((size_t)bG * 512 + tn) * 128 + d];
    if (tid == 0) {
      while (__hip_atomic_load(ctrB, RLX, AGENT) < 8u * (t + 1)) __builtin_amdgcn_s_sleep(1);
    }
    __syncthreads();
    xv = xv_n;
  }
}

// ---------------- host ----------------
extern "C" void kernel_launch(void* const* d_in, const int* in_sizes, int n_in,
                              void* d_out, int out_size, void* d_ws, size_t ws_size,
                              hipStream_t stream) {
  const float* x = (const float*)d_in[0];
  const float* wue = (const float*)d_in[1];
  const float* ve = (const float*)d_in[2];
  const float* wih = (const float*)d_in[3];
  const float* whh = (const float*)d_in[4];
  const float* bih = (const float*)d_in[5];
  const float* bhh = (const float*)d_in[6];
  float* out = (float*)d_out;

  char* ws = (char*)d_ws;
  __hip_bfloat16* px2 = (__hip_bfloat16*)(ws);             // 33,554,432 B
  __hip_bfloat16* whB = (__hip_bfloat16*)(ws + 33554432);  //    524,288 B
  __hip_bfloat16* w3B = (__hip_bfloat16*)(ws + 34078720);  //    786,432 B
  float* bsum = (float*)(ws + 34865152);                   //      4,096 B
  float* Eg = (float*)(ws + 34869248);                     //    262,144 B
  unsigned* ctrs = (unsigned*)(ws + 35131392);             //      8,192 B
  unsigned* hG = (unsigned*)(ws + 35139584);               //  1,048,576 B
  float* wxt = (float*)(ws + 36188160);                    //  1,048,576 B
  // total: 37,236,736 B

  k_pack_whB<<<1024, 256, 0, stream>>>(wue, whB);
  k_pack_w3B<<<1024, 256, 0, stream>>>(wih, whh, w3B);
  k_bsum<<<4, 256, 0, stream>>>(bih, bhh, bsum);
  k_wxt<<<256, 256, 0, stream>>>(wue, wxt);
  k_projx<<<256, 512, 0, stream>>>(x, wxt, px2);
  hipMemsetAsync(hG, 0, 1048576, stream);
  hipMemsetAsync(Eg, 0, 262144, stream);
  hipMemsetAsync(ctrs, 0, 8192, stream);
  k_main<<<256, 1024, 0, stream>>>(px2, whB, w3B, bsum, x, ve, hG, Eg, ctrs, out);
}